// Round 9
// baseline (36.926 us; speedup 1.0000x reference)
//
#include <hip/hip_runtime.h>
#include <math.h>

#define TPB     256
#define COLS2   32             // float2-columns per block (= 64 scalar cols)
#define SEGS    8              // output segments per block (TPB/COLS2)
#define SEGLEN  16             // t's per thread
#define TSPAN   (SEGS * SEGLEN)    // 128 t's per block
#define HSEGLEN 13             // halo rows scanned per thread
#define HALO    (SEGS * HSEGLEN)   // 104 >= reference max nw (100)

// ---------------------------------------------------------------------------
// GARCH sigma, untruncated-IIR formulation (see R5-R8 notes).
//   a[t+1] = beta*a[t] + x2[t],  sigma[t] = sqrt(w0 + alpha*a[t])
// Seed truncated at >=104 taps; vs reference's nw<=100-tap FIR the error is
// the beta^{>=100} tail: measured ~4e-3 vs threshold 1.6e-2.
//
// R9 delta vs R8: float2 everywhere (2 cols/thread) — halves vmem instruction
// count at the 8B/lane coalescing sweet spot; halo 128->104 rows; mixed-radix
// seed Horner (b13 halo, b16 own); dwordx2 NT stores. 32-bit addressing.
// ---------------------------------------------------------------------------

__device__ __forceinline__ float fast_sigmoid(float x) {
    const float LOG2E = 1.4426950408889634f;
    const float e = __builtin_amdgcn_exp2f(-x * LOG2E);
    return __builtin_amdgcn_rcpf(1.0f + e);
}

__global__ __launch_bounds__(TPB) void garch_sigma_kernel(
    const float2* __restrict__ xp,
    const float2* __restrict__ ar2,
    const float2* __restrict__ br2,
    const float2* __restrict__ or2,
    float2*       __restrict__ outp,
    int T, int N2) {

    __shared__ float2 QsH[SEGS][COLS2];   // halo partials (13 rows each)
    __shared__ float2 QsO[SEGS][COLS2];   // own-segment partials (16 rows each)

    const int tid = threadIdx.x;
    const int c2  = tid & (COLS2 - 1);
    const int k   = tid >> 5;                       // segment 0..7
    const int n2  = blockIdx.x * COLS2 + c2;
    const int t0  = blockIdx.y * TSPAN;

    const int  nc     = (n2 < N2) ? n2 : (N2 - 1); // clamp for ragged N
    const bool col_ok = (n2 < N2);

    const float2 arv = ar2[nc];
    const float2 brv = br2[nc];
    const float2 orv = or2[nc];
    const float ax = fast_sigmoid(arv.x), ay = fast_sigmoid(arv.y);
    const float bx = fast_sigmoid(brv.x) * 0.9999f;
    const float by = fast_sigmoid(brv.y) * 0.9999f;
    const float ox = fast_sigmoid(orv.x), oy = fast_sigmoid(orv.y);
    const float w0x = ox * ox * __builtin_amdgcn_rcpf(1.0f - bx);
    const float w0y = oy * oy * __builtin_amdgcn_rcpf(1.0f - by);

    // ---------------- phase 1: issue ALL loads up front -------------------
    const int h0 = t0 - HALO + k * HSEGLEN;         // halo segment start
    const int g0 = t0 + k * SEGLEN;                 // own segment start

    float2 h[HSEGLEN];
    const bool have_halo = (h0 >= 0);               // all-valid or all-zero
    if (have_halo) {
        const int base = h0 * N2 + nc;
        #pragma unroll
        for (int i = 0; i < HSEGLEN; ++i)
            h[i] = xp[base + i * N2];
    }

    float2 p[SEGLEN];
    {
        const int base = g0 * N2 + nc;
        if (t0 + TSPAN <= T) {                      // full tile: no guards
            #pragma unroll
            for (int i = 0; i < SEGLEN; ++i)
                p[i] = xp[base + i * N2];
        } else {
            #pragma unroll
            for (int i = 0; i < SEGLEN; ++i) {
                if (g0 + i < T) p[i] = xp[base + i * N2];
                else            p[i] = make_float2(0.f, 0.f);
            }
        }
    }

    // ---------------- scans -> partials ----------------
    {
        float qx = 0.f, qy = 0.f;
        if (have_halo) {
            #pragma unroll
            for (int i = 0; i < HSEGLEN; ++i) {
                qx = fmaf(bx, qx, h[i].x * h[i].x);
                qy = fmaf(by, qy, h[i].y * h[i].y);
            }
        }
        QsH[k][c2] = make_float2(qx, qy);
    }
    {
        float qx = 0.f, qy = 0.f;
        #pragma unroll
        for (int i = 0; i < SEGLEN; ++i) {
            const float sx = p[i].x * p[i].x;
            const float sy = p[i].y * p[i].y;
            p[i] = make_float2(sx, sy);
            qx = fmaf(bx, qx, sx);
            qy = fmaf(by, qy, sy);
        }
        QsO[k][c2] = make_float2(qx, qy);
    }

    __syncthreads();

    // ------------- phase 2: seed via mixed-radix Horner (b13, b16) --------
    const float bx2 = bx * bx,  by2 = by * by;
    const float bx4 = bx2 * bx2, by4 = by2 * by2;
    const float bx8 = bx4 * bx4, by8 = by4 * by4;
    const float b13x = bx8 * bx4 * bx, b13y = by8 * by4 * by;
    const float b16x = bx8 * bx8,      b16y = by8 * by8;

    float a_x = 0.f, a_y = 0.f;
    #pragma unroll
    for (int u = 0; u < SEGS; ++u) {                // halo, oldest first
        const float2 q = QsH[u][c2];
        a_x = fmaf(a_x, b13x, q.x);
        a_y = fmaf(a_y, b13y, q.y);
    }
    for (int u = 0; u < k; ++u) {                   // own segments before g0
        const float2 q = QsO[u][c2];
        a_x = fmaf(a_x, b16x, q.x);
        a_y = fmaf(a_y, b16y, q.y);
    }

    // ---------------- emit 16 float2 outputs from registers ---------------
    if (col_ok) {
        float2* op = outp + (g0 * N2 + nc);
        if (t0 + TSPAN <= T) {
            #pragma unroll
            for (int i = 0; i < SEGLEN; ++i) {
                float2 sg;
                sg.x = __builtin_amdgcn_sqrtf(fmaf(ax, a_x, w0x));
                sg.y = __builtin_amdgcn_sqrtf(fmaf(ay, a_y, w0y));
                union { float2 f2; double d; } u2; u2.f2 = sg;
                __builtin_nontemporal_store(u2.d, (double*)(op + i * N2));
                a_x = fmaf(bx, a_x, p[i].x);
                a_y = fmaf(by, a_y, p[i].y);
            }
        } else {
            #pragma unroll
            for (int i = 0; i < SEGLEN; ++i) {
                float2 sg;
                sg.x = __builtin_amdgcn_sqrtf(fmaf(ax, a_x, w0x));
                sg.y = __builtin_amdgcn_sqrtf(fmaf(ay, a_y, w0y));
                if (g0 + i < T) {
                    union { float2 f2; double d; } u2; u2.f2 = sg;
                    __builtin_nontemporal_store(u2.d, (double*)(op + i * N2));
                }
                a_x = fmaf(bx, a_x, p[i].x);
                a_y = fmaf(by, a_y, p[i].y);
            }
        }
    }
}

// ---------------------------------------------------------------------------
extern "C" void kernel_launch(void* const* d_in, const int* in_sizes, int n_in,
                              void* d_out, int out_size, void* d_ws, size_t ws_size,
                              hipStream_t stream) {
    const float* x   = (const float*)d_in[0];
    const float* ar  = (const float*)d_in[1];
    const float* br  = (const float*)d_in[2];
    const float* orw = (const float*)d_in[3];
    float* out = (float*)d_out;

    const int N  = in_sizes[1];         // alpha_raw is [1, N]
    const int T  = in_sizes[0] / N;     // x is [T, N]
    const int N2 = N >> 1;

    dim3 grid((N2 + COLS2 - 1) / COLS2, (T + TSPAN - 1) / TSPAN);
    hipLaunchKernelGGL(garch_sigma_kernel, grid, dim3(TPB), 0, stream,
                       (const float2*)x, (const float2*)ar, (const float2*)br,
                       (const float2*)orw, (float2*)out, T, N2);
}